// Round 13
// baseline (325.141 us; speedup 1.0000x reference)
//
#include <hip/hip_runtime.h>
#include <stdint.h>
#include <math.h>

typedef unsigned short u16;
typedef __attribute__((ext_vector_type(8))) short short8;
typedef __attribute__((ext_vector_type(8))) _Float16 half8;
typedef __attribute__((ext_vector_type(4))) float float4v;
typedef __attribute__((ext_vector_type(16))) float float16v;
typedef __attribute__((ext_vector_type(4))) u16 ushort4v;

#define T_SEQ 2048
#define NB 2
#define NE 2048
#define NH 16
#define NKV 4
#define HD 128
#define KDIM 2048

union Frag { short8 s; half8 h; };

__device__ inline u16 f32_bf16(float f) {
    union { float f; uint32_t u; } v; v.f = f;
    uint32_t u = v.u;
    return (u16)((u + 0x7fffu + ((u >> 16) & 1u)) >> 16);
}
__device__ inline u16 f32_f16(float f) {
    union { _Float16 h; u16 u; } v; v.h = (_Float16)f;
    return v.u;
}

// v_cvt_pk_bf16_f32: dst.lo = bf16(lo), dst.hi = bf16(hi)  (RNE)
__device__ inline uint32_t cvtpk_bf16(float lo, float hi) {
    uint32_t r;
    asm("v_cvt_pk_bf16_f32 %0, %1, %2" : "=v"(r) : "v"(lo), "v"(hi));
    return r;
}
// v_permlane32_swap_b32: a.lanes[32+i] <-> b.lanes[i]
// after: a = [a.lo | b.lo], b = [a.hi | b.hi]
__device__ inline void perm32swap(uint32_t& a, uint32_t& b) {
    asm("v_permlane32_swap_b32 %0, %1" : "+v"(a), "+v"(b));
}

// async global->LDS, 16B per lane; LDS dest = wave-uniform base + lane*16
typedef __attribute__((address_space(1))) const void g_void;
typedef __attribute__((address_space(3))) void l_void;
#define GLOAD16(g, l) __builtin_amdgcn_global_load_lds((g_void*)(g), (l_void*)(l), 16, 0, 0)

// ---------------- prep kernels ----------------
// R12 lesson: fully fusing conv+transposes+rope into ONE 14848-block launch
// regressed gemm_qkv 80->102us with byte-identical GEMM code (hbm_gbps
// 1315->1035, MfmaUtil 26->20.5, FETCH unchanged) -- phase BLENDING inside
// one launch (conv's 48MB stream concurrent with transpose traffic) leaves a
// worse memory-subsystem state than hard launch boundaries. A/B: split along
// R11's phase boundary, keeping 3 fewer launches than R11 (6 total).
__global__ __launch_bounds__(256)
void conv_f16(const float* __restrict__ in, u16* __restrict__ out) {
    int i = blockIdx.x * blockDim.x + threadIdx.x;
    float4 v = ((const float4*)in)[i];
    ushort4v o;
    o.x = f32_f16(v.x); o.y = f32_f16(v.y); o.z = f32_f16(v.z); o.w = f32_f16(v.w);
    *(ushort4v*)(out + (size_t)i * 4) = o;
}

// W transposes (f32->f16) + rope tables, one launch, block-range decode.
// bid: [0,4096) Wq^T | [4096,5120) Wk^T | [5120,6144) Wv^T | [6144,6656) rope
__global__ __launch_bounds__(256)
void prep_wt(const float* __restrict__ Wq, u16* __restrict__ wqt,
             const float* __restrict__ Wk, u16* __restrict__ wkt,
             const float* __restrict__ Wv, u16* __restrict__ wvt,
             float* __restrict__ ctab, float* __restrict__ stab) {
    __shared__ float tile[32][33];
    int bid = blockIdx.x, tid = threadIdx.x;
    if (bid < 6144) {                      // W (K=2048 x N) -> W^T (N x 2048), f16
        const float* in; u16* out; int N, b;
        if (bid < 4096)      { in = Wq; out = wqt; N = 2048; b = bid;        }
        else if (bid < 5120) { in = Wk; out = wkt; N = 512;  b = bid - 4096; }
        else                 { in = Wv; out = wvt; N = 512;  b = bid - 5120; }
        int nb = N >> 5;                   // grid was dim3(N/32, 64), x-major
        int n0 = (b % nb) * 32, k0 = (b / nb) * 32;
        int tx = tid & 31, ty = tid >> 5;  // 32 x 8
        for (int i = 0; i < 32; i += 8)
            tile[ty + i][tx] = in[(size_t)(k0 + ty + i) * N + n0 + tx];
        __syncthreads();
        for (int i = 0; i < 32; i += 8)
            out[(size_t)(n0 + ty + i) * 2048 + k0 + tx] = f32_f16(tile[tx][ty + i]);
    } else {                               // rope cos/sin tables
        int i = (bid - 6144) * 256 + tid;  // < 2048*64
        int t = i >> 6, j = i & 63;
        float freqf = (float)pow(10000.0, -(double)j / 1024.0);
        float angf = (float)t * freqf;     // fp32 rounding like np.outer
        double a = (double)angf;
        ctab[i] = (float)cos(a);
        stab[i] = (float)sin(a);
    }
}

// Wo transpose (f32 -> bf16) kept separate: wot aliases wqt, which gemm_qkv
// still reads -- the launch boundary after gemm_qkv is the fence.
__global__ void transpose_wo(const float* __restrict__ in, u16* __restrict__ out) {
    __shared__ float tile[32][33];
    int n0 = blockIdx.x * 32, k0 = blockIdx.y * 32;
    int tx = threadIdx.x, ty = threadIdx.y;   // 32 x 8
    for (int i = 0; i < 32; i += 8)
        tile[ty + i][tx] = in[(size_t)(k0 + ty + i) * 2048 + n0 + tx];
    __syncthreads();
    for (int i = 0; i < 32; i += 8)
        out[(size_t)(n0 + ty + i) * 2048 + k0 + tx] = f32_bf16(tile[tx][ty + i]);
}

// ---------------- GEMM main loop: depth-2 pipeline, 3 static buffer pairs ----------------
// (R11, verified: gemm_qkv 90->80us, MfmaUtil 23.5->26.5.) 3 buffer pairs
// (48KB, 3 blocks/CU), stage substep t+2 before computing t, steady-state
// vmcnt(8) (substeps t+1,t+2 in flight = 8 loads/wave). 3-phase unroll keeps
// every LDS address compile-time static (rule #20). Overwrite safety:
// stage(t+2) targets the buffer read at t-1, separated by the lgkmcnt(0)+
// barrier after compute(t-1). Bank swizzle (R10, conflicts 6.29M->0) kept.
#define GEMM_WAITBAR8() \
    __builtin_amdgcn_sched_barrier(0); \
    asm volatile("s_waitcnt vmcnt(8)" ::: "memory"); \
    asm volatile("s_barrier" ::: "memory"); \
    __builtin_amdgcn_sched_barrier(0);
#define GEMM_WAITBAR4() \
    __builtin_amdgcn_sched_barrier(0); \
    asm volatile("s_waitcnt vmcnt(4)" ::: "memory"); \
    asm volatile("s_barrier" ::: "memory"); \
    __builtin_amdgcn_sched_barrier(0);
#define GEMM_WAITBAR0() \
    __builtin_amdgcn_sched_barrier(0); \
    asm volatile("s_waitcnt vmcnt(0)" ::: "memory"); \
    asm volatile("s_barrier" ::: "memory"); \
    __builtin_amdgcn_sched_barrier(0);
#define GEMM_READBAR() \
    __builtin_amdgcn_sched_barrier(0); \
    asm volatile("s_waitcnt lgkmcnt(0)" ::: "memory"); \
    asm volatile("s_barrier" ::: "memory"); \
    __builtin_amdgcn_sched_barrier(0);

#define GEMM_STAGE_DECL(Asrc, Bsrc) \
    int rin = lane >> 2; \
    int ksl = (lane & 3) ^ ((lane >> 3) & 3);   /* swizzled source k-slot */ \
    int u0r = wid * 32; \
    const u16* Ag0 = (Asrc) + (size_t)(m0 + u0r + rin) * KDIM + ksl * 8; \
    const u16* Ag1 = (Asrc) + (size_t)(m0 + u0r + 16 + rin) * KDIM + ksl * 8; \
    const u16* Bg0 = (Bsrc) + (size_t)(n0 + u0r + rin) * KDIM + ksl * 8; \
    const u16* Bg1 = (Bsrc) + (size_t)(n0 + u0r + 16 + rin) * KDIM + ksl * 8; \
    int xquad = quad ^ ((l16 >> 1) & 3);        /* swizzled read slot */

#define GEMM_STAGE(Abuf, Bbuf, kk) \
    GLOAD16(Ag0 + (kk), &Abuf[u0r * 32]); \
    GLOAD16(Ag1 + (kk), &Abuf[(u0r + 16) * 32]); \
    GLOAD16(Bg0 + (kk), &Bbuf[u0r * 32]); \
    GLOAD16(Bg1 + (kk), &Bbuf[(u0r + 16) * 32]);

#define GEMM_COMPUTE(Abuf, Bbuf, F16) { \
    Frag af[4], bf[4]; \
    for (int i = 0; i < 4; i++) \
        af[i].s = *(const short8*)&Abuf[(wr * 64 + i * 16 + l16) * 32 + xquad * 8]; \
    for (int j = 0; j < 4; j++) \
        bf[j].s = *(const short8*)&Bbuf[(wc * 64 + j * 16 + l16) * 32 + xquad * 8]; \
    for (int i = 0; i < 4; i++) \
        for (int j = 0; j < 4; j++) { \
            if (F16) \
                acc[i][j] = __builtin_amdgcn_mfma_f32_16x16x32_f16(af[i].h, bf[j].h, acc[i][j], 0, 0, 0); \
            else \
                acc[i][j] = __builtin_amdgcn_mfma_f32_16x16x32_bf16(af[i].s, bf[j].s, acc[i][j], 0, 0, 0); \
        } \
}

#define GEMM_PHASE(Ac, Bc, An, Bn, tt, F16) \
    GEMM_STAGE(An, Bn, ((tt) + 2) * 32) \
    GEMM_WAITBAR8() \
    GEMM_COMPUTE(Ac, Bc, F16) \
    GEMM_READBAR()

#define GEMM_MAINLOOP(F16) \
    GEMM_STAGE(A0s, B0s, 0) \
    GEMM_STAGE(A1s, B1s, 32) \
    for (int t = 0; t < 60; t += 3) { \
        GEMM_PHASE(A0s, B0s, A2s, B2s, t,     F16) \
        GEMM_PHASE(A1s, B1s, A0s, B0s, t + 1, F16) \
        GEMM_PHASE(A2s, B2s, A1s, B1s, t + 2, F16) \
    } \
    GEMM_PHASE(A0s, B0s, A2s, B2s, 60, F16)   /* stages substep 62 */ \
    GEMM_PHASE(A1s, B1s, A0s, B0s, 61, F16)   /* stages substep 63 */ \
    GEMM_WAITBAR4() \
    GEMM_COMPUTE(A2s, B2s, F16)               /* substep 62 */ \
    GEMM_READBAR() \
    GEMM_WAITBAR0() \
    GEMM_COMPUTE(A0s, B0s, F16)               /* substep 63 */

// ---------------- fused Q+K+V projection: 1D grid of 768 equal-cost blocks ----------------
// XCD-aware swizzle (T1): 768%8==0, bijective chunk map lin=(bid&7)*96+(bid>>3)
// (FETCH 112->78MB measured in R9).
// lin <  512: Q:  C[t,d] = xh @ wqt^T, rope -> [B,NH,T,D]
// 512..639 : K:  C[t,d] = xh @ wkt^T, rope -> [B,NKV,T,D]
// 640..767 : V^T by operand swap: A = wvt (rows d=512), Bt = xh (rows t=4096)
//            -> C[d,t], write [B,NKV,D,T] coalesced along t.
__global__ __launch_bounds__(256)
void gemm_qkv(const u16* __restrict__ xh, const u16* __restrict__ wqt,
              const u16* __restrict__ wkt, const u16* __restrict__ wvt,
              const float* __restrict__ bq, const float* __restrict__ bk,
              const float* __restrict__ bv,
              u16* __restrict__ qout, u16* __restrict__ kout, u16* __restrict__ vout,
              const float* __restrict__ ctab, const float* __restrict__ stab) {
    __shared__ u16 A0s[128 * 32], A1s[128 * 32], A2s[128 * 32];
    __shared__ u16 B0s[128 * 32], B1s[128 * 32], B2s[128 * 32];
    int tid = threadIdx.x;
    int wid = tid >> 6, lane = tid & 63;
    int quad = lane >> 4, l16 = lane & 15;
    int wr = wid >> 1, wc = wid & 1;

    int bid = blockIdx.x;
    int lin = (bid & 7) * 96 + (bid >> 3);   // XCD swizzle, bijective on 768
    int mode, m0, n0;
    const u16 *A, *Bt;
    if (lin < 512) {          // Q
        mode = 0; m0 = (lin >> 4) * 128; n0 = (lin & 15) * 128; A = xh; Bt = wqt;
    } else if (lin < 640) {   // K
        int i = lin - 512;
        mode = 1; m0 = (i >> 2) * 128; n0 = (i & 3) * 128; A = xh; Bt = wkt;
    } else {                  // V (swapped)
        int i = lin - 640;
        mode = 2; m0 = (i & 3) * 128; n0 = (i >> 2) * 128; A = wvt; Bt = xh;
    }

    float4v acc[4][4];
    for (int i = 0; i < 4; i++) for (int j = 0; j < 4; j++) acc[i][j] = (float4v){0,0,0,0};

    GEMM_STAGE_DECL(A, Bt)
    GEMM_MAINLOOP(true)

    if (mode == 2) {
        // rows m = global d (h = m>>7, d = m&127); cols = global t (b = col>>11)
        for (int i = 0; i < 4; i++) {
            int mbase = m0 + wr * 64 + i * 16 + quad * 4;
            float brow[4];
            for (int r = 0; r < 4; r++) brow[r] = bv[mbase + r];
            for (int j = 0; j < 4; j++) {
                int col = n0 + wc * 64 + j * 16 + l16;
                int b = col >> 11, t = col & 2047;
                for (int r = 0; r < 4; r++) {
                    int m = mbase + r;
                    float val = acc[i][j][r] + brow[r];
                    vout[(((size_t)(b * NKV + (m >> 7))) * HD + (m & 127)) * T_SEQ + t] = f32_bf16(val);
                }
            }
        }
    } else {
        const float* bias = mode ? bk : bq;
        u16* outU = mode ? kout : qout;
        int nheads = mode ? NKV : NH;
        for (int i = 0; i < 4; i++) {
            int mbase = m0 + wr * 64 + i * 16 + quad * 4;
            for (int j = 0; j < 4; j++) {
                int col = n0 + wc * 64 + j * 16 + l16;
                float bcol = bias[col];
                for (int r = 0; r < 4; r++) {
                    int m = mbase + r;
                    float val = acc[i][j][r] + bcol;
                    int b = m >> 11, t = m & 2047;
                    int h = col >> 7, d = col & 127;
                    int jj = d >> 1;
                    float c = ctab[t * 64 + jj];
                    float s = stab[t * 64 + jj];
                    float partner = __shfl_xor(val, 1, 64);
                    float o = (d & 1) ? (partner * s + val * c) : (val * c - partner * s);
                    outU[(((size_t)(b * nheads + h)) * T_SEQ + t) * HD + d] = f32_bf16(o);
                }
            }
        }
    }
}

// ---------------- output projection GEMM (bf16 in, fp32 + bias out) ----------------
// 1-D grid of 512 with the same XCD swizzle (512%8==0, cpx=64).
__global__ __launch_bounds__(256)
void gemm_out(const u16* __restrict__ A, const u16* __restrict__ Bt,
              const float* __restrict__ bias, float* __restrict__ outF) {
    __shared__ u16 A0s[128 * 32], A1s[128 * 32], A2s[128 * 32];
    __shared__ u16 B0s[128 * 32], B1s[128 * 32], B2s[128 * 32];
    int tid = threadIdx.x;
    int wid = tid >> 6, lane = tid & 63;
    int quad = lane >> 4, l16 = lane & 15;
    int wr = wid >> 1, wc = wid & 1;
    int bid = blockIdx.x;
    int lin = (bid & 7) * 64 + (bid >> 3);   // XCD swizzle, bijective on 512
    int m0 = (lin >> 4) * 128, n0 = (lin & 15) * 128;

    float4v acc[4][4];
    for (int i = 0; i < 4; i++) for (int j = 0; j < 4; j++) acc[i][j] = (float4v){0,0,0,0};

    GEMM_STAGE_DECL(A, Bt)
    GEMM_MAINLOOP(false)

    for (int i = 0; i < 4; i++) {
        int mbase = m0 + wr * 64 + i * 16 + quad * 4;
        for (int j = 0; j < 4; j++) {
            int col = n0 + wc * 64 + j * 16 + l16;
            float bcol = bias[col];
            for (int r = 0; r < 4; r++)
                outF[(size_t)(mbase + r) * NE + col] = acc[i][j][r] + bcol;
        }
    }
}

// ---------------- flash attention v4 ----------------
// v3h + (T12) in-register P via cvt_pk+permlane32_swap (plds removed: -18.4KB
// LDS, -1 barrier/tile), (T13) defer-max THR=8, (T5) setprio around MFMA
// clusters, fully-masked diagonal-tile skip for waves 0,1.
__global__ __launch_bounds__(256, 2)
void attn_kernel(const u16* __restrict__ Qr, const u16* __restrict__ Kr,
                 const u16* __restrict__ Vt, u16* __restrict__ Oout) {
    __shared__ u16 smem[17920];            // 35840 B
    u16* klds = smem;                      // K tile [s=64][d=128] stride 136
    u16* vlds = smem + 8704;               // V^T tile [d=128][s=64] stride 72
    int tid = threadIdx.x;
    int wid = tid >> 6, lane = tid & 63;
    int l32 = lane & 31, hh = lane >> 5;

    int lin = blockIdx.x + (blockIdx.y << 4);
    int g = lin >> 5, bh = lin & 31;
    int qt = (lin < 256) ? (15 - g) : (g - 8);   // balance: CU gets qt and 15-qt
    int b = bh >> 4, hd = bh & 15, kvh = hd >> 2;
    int t0 = qt * 128;

    const u16* Qb = Qr + (((size_t)(b * NH + hd)) * T_SEQ + t0 + wid * 32) * HD;
    const u16* Kb = Kr + ((size_t)(b * NKV + kvh)) * T_SEQ * HD;
    const u16* Vb = Vt + ((size_t)(b * NKV + kvh)) * HD * T_SEQ;

    // Q as B-operand frags: col = t = l32, k = d
    short8 qf[8];
#pragma unroll
    for (int ks = 0; ks < 8; ks++)
        qf[ks] = *(const short8*)(Qb + (size_t)l32 * HD + ks * 16 + hh * 8);

    float16v oacc[4];   // O^T: rows d (dt*32 block), cols t (= l32)
#pragma unroll
    for (int dt = 0; dt < 4; dt++)
        oacc[dt] = (float16v){0,0,0,0,0,0,0,0,0,0,0,0,0,0,0,0};
    float m_run = -INFINITY, l_run = 0.f;

    int ksr = tid >> 2, kc = (tid & 3) * 32;   // K staging: row s, col base (u16)
    int vdr = tid >> 1, vc = (tid & 1) * 32;   // V staging: row d, col base (u16)

    int nst = 2 * qt + 2;

    {   // prologue: stage tile 0
        const u16* ksrc = Kb + (size_t)ksr * HD + kc;
        const u16* vsrc = Vb + (size_t)vdr * T_SEQ + vc;
        short8 kr0[4], vr0[4];
#pragma unroll
        for (int i = 0; i < 4; i++) kr0[i] = *(const short8*)(ksrc + i * 8);
#pragma unroll
        for (int i = 0; i < 4; i++) vr0[i] = *(const short8*)(vsrc + i * 8);
#pragma unroll
        for (int i = 0; i < 4; i++) *(short8*)&klds[ksr * 136 + kc + i * 8] = kr0[i];
#pragma unroll
        for (int i = 0; i < 4; i++) *(short8*)&vlds[vdr * 72 + vc + i * 8] = vr0[i];
    }
    __syncthreads();

    for (int st = 0; st < nst; st++) {
        short8 krg[4], vrg[4];
        bool more = (st + 1 < nst);
        if (more) {   // prefetch next K/V tile into registers
            const u16* ksrc = Kb + ((size_t)(st + 1) * 64 + ksr) * HD + kc;
            const u16* vsrc = Vb + (size_t)vdr * T_SEQ + (st + 1) * 64 + vc;
#pragma unroll
            for (int i = 0; i < 4; i++) krg[i] = *(const short8*)(ksrc + i * 8);
#pragma unroll
            for (int i = 0; i < 4; i++) vrg[i] = *(const short8*)(vsrc + i * 8);
        }

        // wave-uniform skip: tile entirely above this wave's causal diagonal
        // (only st == 2qt+1 for waves 0,1). Barriers stay outside.
        bool active = (st * 64) <= (t0 + wid * 32 + 31);
        if (active) {
            // S^T = K * Q^T : rows = s (2 tiles of 32), cols = t (32)
            float16v sfa[2];
            sfa[0] = (float16v){0,0,0,0,0,0,0,0,0,0,0,0,0,0,0,0};
            sfa[1] = (float16v){0,0,0,0,0,0,0,0,0,0,0,0,0,0,0,0};
            __builtin_amdgcn_s_setprio(1);
#pragma unroll
            for (int ks = 0; ks < 8; ks++) {
                short8 kf0 = *(const short8*)&klds[l32 * 136 + ks * 16 + hh * 8];
                short8 kf1 = *(const short8*)&klds[(32 + l32) * 136 + ks * 16 + hh * 8];
                sfa[0] = __builtin_amdgcn_mfma_f32_32x32x16_bf16(kf0, qf[ks], sfa[0], 0, 0, 0);
                sfa[1] = __builtin_amdgcn_mfma_f32_32x32x16_bf16(kf1, qf[ks], sfa[1], 0, 0, 0);
            }
            __builtin_amdgcn_s_setprio(0);

            int tg = t0 + wid * 32 + l32;
            if (st >= 2 * qt) {   // causal mask on diagonal tiles
#pragma unroll
                for (int stile = 0; stile < 2; stile++)
#pragma unroll
                    for (int r = 0; r < 16; r++) {
                        int s = st * 64 + stile * 32 + (r & 3) + 8 * (r >> 2) + 4 * hh;
                        if (s > tg) sfa[stile][r] = -INFINITY;
                    }
            }

            // online softmax over s; T13 defer-max: skip O-rescale while the
            // tile max stays within 8 of the running max (P bounded by e^8).
            float mx = -INFINITY;
#pragma unroll
            for (int stile = 0; stile < 2; stile++)
#pragma unroll
                for (int r = 0; r < 16; r++) mx = fmaxf(mx, sfa[stile][r]);
            mx = fmaxf(mx, __shfl_xor(mx, 32, 64));
            bool nos = __all(mx - m_run <= 8.f);   // wave-uniform
            float mnew = nos ? m_run : fmaxf(m_run, mx);
            float alpha = nos ? 1.f : __expf(m_run - mnew);
            float psum = 0.f;
#pragma unroll
            for (int stile = 0; stile < 2; stile++)
#pragma unroll
                for (int r = 0; r < 16; r++) {
                    float p = __expf(sfa[stile][r] - mnew);
                    sfa[stile][r] = p;
                    psum += p;
                }
            psum += __shfl_xor(psum, 32, 64);
            l_run = l_run * alpha + psum;
            m_run = mnew;

            if (!nos) {
#pragma unroll
                for (int dt = 0; dt < 4; dt++)
#pragma unroll
                    for (int r = 0; r < 16; r++) oacc[dt][r] *= alpha;
            }

            // T12: P^T -> B-operand fragments entirely in registers.
            // Accumulator holds s_local=(r&3)+8(r>>2)+4hh; the B-operand needs
            // k=s=hh*8+e per 16-block. swap(P0,P2)/(P1,P3) redistributes the
            // 4-element groups across the lane halves: after swap,
            // P0=[lo|lo'], P2=[hi|hi'] which is exactly word0/word2 for both hh.
            __builtin_amdgcn_s_setprio(1);
#pragma unroll
            for (int g2 = 0; g2 < 4; g2++) {           // s16-block = ks2
                int stile = g2 >> 1, gg = g2 & 1;
                uint32_t P0 = cvtpk_bf16(sfa[stile][8 * gg + 0], sfa[stile][8 * gg + 1]);
                uint32_t P1 = cvtpk_bf16(sfa[stile][8 * gg + 2], sfa[stile][8 * gg + 3]);
                uint32_t P2 = cvtpk_bf16(sfa[stile][8 * gg + 4], sfa[stile][8 * gg + 5]);
                uint32_t P3 = cvtpk_bf16(sfa[stile][8 * gg + 6], sfa[stile][8 * gg + 7]);
                perm32swap(P0, P2);
                perm32swap(P1, P3);
                union { uint32_t w[4]; short8 s; } pf;
                pf.w[0] = P0; pf.w[1] = P1; pf.w[2] = P2; pf.w[3] = P3;
#pragma unroll
                for (int dt = 0; dt < 4; dt++) {
                    short8 vf = *(const short8*)&vlds[(dt * 32 + l32) * 72 + g2 * 16 + hh * 8];
                    oacc[dt] = __builtin_amdgcn_mfma_f32_32x32x16_bf16(vf, pf.s, oacc[dt], 0, 0, 0);
                }
            }
            __builtin_amdgcn_s_setprio(0);
        }

        __syncthreads();   // all K/V reads done before overwrite
        if (more) {
#pragma unroll
            for (int i = 0; i < 4; i++) *(short8*)&klds[ksr * 136 + kc + i * 8] = krg[i];
#pragma unroll
            for (int i = 0; i < 4; i++) *(short8*)&vlds[vdr * 72 + vc + i * 8] = vrg[i];
        }
        __syncthreads();   // staging visible before next iteration's reads
    }

    // epilogue: scale (per-lane), transpose O^T -> O via LDS scratch
    const float scale = 0.022097086912079608f;   // 2048^-0.5
    float sc = scale / l_run;
    u16* ow = smem + wid * 4352;           // [t=32][d=128] stride 136
#pragma unroll
    for (int dt = 0; dt < 4; dt++)
#pragma unroll
        for (int gq = 0; gq < 4; gq++) {
            ushort4v pk;
            pk.x = f32_bf16(oacc[dt][gq * 4 + 0] * sc);
            pk.y = f32_bf16(oacc[dt][gq * 4 + 1] * sc);
            pk.z = f32_bf16(oacc[dt][gq * 4 + 2] * sc);
            pk.w = f32_bf16(oacc[dt][gq * 4 + 3] * sc);
            *(ushort4v*)&ow[l32 * 136 + dt * 32 + gq * 8 + hh * 4] = pk;
        }
    __syncthreads();   // transpose writes visible before read-back
    int tl = lane >> 4, dcol = (lane & 15) * 8;
#pragma unroll
    for (int ch = 0; ch < 8; ch++) {
        int t_local = tl + ch * 4;
        short8 ov = *(const short8*)&ow[t_local * 136 + dcol];
        *(short8*)&Oout[((size_t)(b * T_SEQ) + t0 + wid * 32 + t_local) * NE + hd * HD + dcol] = ov;
    }
}

// ---------------- launch ----------------
extern "C" void kernel_launch(void* const* d_in, const int* in_sizes, int n_in,
                              void* d_out, int out_size, void* d_ws, size_t ws_size,
                              hipStream_t stream) {
    const float* x  = (const float*)d_in[0];
    const float* Wq = (const float*)d_in[1];
    const float* bq = (const float*)d_in[2];
    const float* Wk = (const float*)d_in[3];
    const float* bk = (const float*)d_in[4];
    const float* Wv = (const float*)d_in[5];
    const float* bv = (const float*)d_in[6];
    const float* Wo = (const float*)d_in[7];
    const float* bo = (const float*)d_in[8];
    float* out = (float*)d_out;
    char* ws = (char*)d_ws;

    // aliasing: ao reuses xh (xh dead after QKV gemm); wot reuses wqt (dead after QKV gemm)
    u16* xh   = (u16*)(ws);                      // 16 MB   [also ao]
    u16* wqt  = (u16*)(ws + 16777216);           // 8 MB    [also wot]
    u16* wkt  = (u16*)(ws + 25165824);           // 2 MB
    u16* wvt  = (u16*)(ws + 27262976);           // 2 MB
    u16* qr   = (u16*)(ws + 29360128);           // 16 MB
    u16* kr   = (u16*)(ws + 46137344);           // 4 MB
    u16* vt   = (u16*)(ws + 50331648);           // 4 MB
    float* ctab = (float*)(ws + 54525952);       // 0.5 MB
    float* stab = (float*)(ws + 55050240);       // 0.5 MB
    u16* ao  = xh;
    u16* wot = wqt;

    conv_f16<<<dim3(8192), 256, 0, stream>>>(x, xh);
    prep_wt<<<dim3(6656), 256, 0, stream>>>(Wq, wqt, Wk, wkt, Wv, wvt, ctab, stab);

    gemm_qkv<<<dim3(768), 256, 0, stream>>>(xh, wqt, wkt, wvt, bq, bk, bv,
                                            qr, kr, vt, ctab, stab);

    // Wo transpose after QKV gemm (wqt dead), before final gemm
    transpose_wo<<<dim3(64, 64), dim3(32, 8), 0, stream>>>(Wo, wot);

    attn_kernel<<<dim3(16, 32), 256, 0, stream>>>(qr, kr, vt, ao);

    gemm_out<<<dim3(512), 256, 0, stream>>>(ao, wot, bo, out);
}

// Round 14
// 306.236 us; speedup vs baseline: 1.0617x; 1.0617x over previous
//
#include <hip/hip_runtime.h>
#include <stdint.h>
#include <math.h>

typedef unsigned short u16;
typedef __attribute__((ext_vector_type(8))) short short8;
typedef __attribute__((ext_vector_type(8))) _Float16 half8;
typedef __attribute__((ext_vector_type(4))) float float4v;
typedef __attribute__((ext_vector_type(16))) float float16v;
typedef __attribute__((ext_vector_type(4))) u16 ushort4v;

#define T_SEQ 2048
#define NB 2
#define NE 2048
#define NH 16
#define NKV 4
#define HD 128
#define KDIM 2048

union Frag { short8 s; half8 h; };

__device__ inline u16 f32_bf16(float f) {
    union { float f; uint32_t u; } v; v.f = f;
    uint32_t u = v.u;
    return (u16)((u + 0x7fffu + ((u >> 16) & 1u)) >> 16);
}
__device__ inline u16 f32_f16(float f) {
    union { _Float16 h; u16 u; } v; v.h = (_Float16)f;
    return v.u;
}

// v_cvt_pk_bf16_f32: dst.lo = bf16(lo), dst.hi = bf16(hi)  (RNE)
__device__ inline uint32_t cvtpk_bf16(float lo, float hi) {
    uint32_t r;
    asm("v_cvt_pk_bf16_f32 %0, %1, %2" : "=v"(r) : "v"(lo), "v"(hi));
    return r;
}
// v_permlane32_swap_b32: a.lanes[32+i] <-> b.lanes[i]
// after: a = [a.lo | b.lo], b = [a.hi | b.hi]
__device__ inline void perm32swap(uint32_t& a, uint32_t& b) {
    asm("v_permlane32_swap_b32 %0, %1" : "+v"(a), "+v"(b));
}

// async global->LDS, 16B per lane; LDS dest = wave-uniform base + lane*16
typedef __attribute__((address_space(1))) const void g_void;
typedef __attribute__((address_space(3))) void l_void;
#define GLOAD16(g, l) __builtin_amdgcn_global_load_lds((g_void*)(g), (l_void*)(l), 16, 0, 0)

// ---------------- prep kernels ----------------
// R12/R13 A/B: fusing conv into the transpose launch regressed the DOWNSTREAM
// gemm_qkv 80->102us (phase blending / cache-state effect); keep conv and the
// W-transposes in separate launches (R13 restored qkv to 80.4us).
__global__ __launch_bounds__(256)
void conv_f16(const float* __restrict__ in, u16* __restrict__ out) {
    int i = blockIdx.x * blockDim.x + threadIdx.x;
    float4 v = ((const float4*)in)[i];
    ushort4v o;
    o.x = f32_f16(v.x); o.y = f32_f16(v.y); o.z = f32_f16(v.z); o.w = f32_f16(v.w);
    *(ushort4v*)(out + (size_t)i * 4) = o;
}

// W transposes (f32->f16) + rope tables, one launch, block-range decode.
// bid: [0,4096) Wq^T | [4096,5120) Wk^T | [5120,6144) Wv^T | [6144,6656) rope
__global__ __launch_bounds__(256)
void prep_wt(const float* __restrict__ Wq, u16* __restrict__ wqt,
             const float* __restrict__ Wk, u16* __restrict__ wkt,
             const float* __restrict__ Wv, u16* __restrict__ wvt,
             float* __restrict__ ctab, float* __restrict__ stab) {
    __shared__ float tile[32][33];
    int bid = blockIdx.x, tid = threadIdx.x;
    if (bid < 6144) {                      // W (K=2048 x N) -> W^T (N x 2048), f16
        const float* in; u16* out; int N, b;
        if (bid < 4096)      { in = Wq; out = wqt; N = 2048; b = bid;        }
        else if (bid < 5120) { in = Wk; out = wkt; N = 512;  b = bid - 4096; }
        else                 { in = Wv; out = wvt; N = 512;  b = bid - 5120; }
        int nb = N >> 5;                   // grid was dim3(N/32, 64), x-major
        int n0 = (b % nb) * 32, k0 = (b / nb) * 32;
        int tx = tid & 31, ty = tid >> 5;  // 32 x 8
        for (int i = 0; i < 32; i += 8)
            tile[ty + i][tx] = in[(size_t)(k0 + ty + i) * N + n0 + tx];
        __syncthreads();
        for (int i = 0; i < 32; i += 8)
            out[(size_t)(n0 + ty + i) * 2048 + k0 + tx] = f32_f16(tile[tx][ty + i]);
    } else {                               // rope cos/sin tables
        int i = (bid - 6144) * 256 + tid;  // < 2048*64
        int t = i >> 6, j = i & 63;
        float freqf = (float)pow(10000.0, -(double)j / 1024.0);
        float angf = (float)t * freqf;     // fp32 rounding like np.outer
        double a = (double)angf;
        ctab[i] = (float)cos(a);
        stab[i] = (float)sin(a);
    }
}

// ---------------- GEMM main loop: depth-2 pipeline, 3 static buffer pairs ----------------
// (R11, verified: gemm_qkv 90->80us, MfmaUtil 23.5->26.5.) 3 buffer pairs
// (48KB, 3 blocks/CU), stage substep t+2 before computing t, steady-state
// vmcnt(8) (substeps t+1,t+2 in flight = 8 loads/wave). 3-phase unroll keeps
// every LDS address compile-time static (rule #20). Overwrite safety:
// stage(t+2) targets the buffer read at t-1, separated by the lgkmcnt(0)+
// barrier after compute(t-1). Bank swizzle (R10, conflicts 6.29M->0) kept.
#define GEMM_WAITBAR8() \
    __builtin_amdgcn_sched_barrier(0); \
    asm volatile("s_waitcnt vmcnt(8)" ::: "memory"); \
    asm volatile("s_barrier" ::: "memory"); \
    __builtin_amdgcn_sched_barrier(0);
#define GEMM_WAITBAR4() \
    __builtin_amdgcn_sched_barrier(0); \
    asm volatile("s_waitcnt vmcnt(4)" ::: "memory"); \
    asm volatile("s_barrier" ::: "memory"); \
    __builtin_amdgcn_sched_barrier(0);
#define GEMM_WAITBAR0() \
    __builtin_amdgcn_sched_barrier(0); \
    asm volatile("s_waitcnt vmcnt(0)" ::: "memory"); \
    asm volatile("s_barrier" ::: "memory"); \
    __builtin_amdgcn_sched_barrier(0);
#define GEMM_READBAR() \
    __builtin_amdgcn_sched_barrier(0); \
    asm volatile("s_waitcnt lgkmcnt(0)" ::: "memory"); \
    asm volatile("s_barrier" ::: "memory"); \
    __builtin_amdgcn_sched_barrier(0);

#define GEMM_STAGE_DECL(Asrc, Bsrc) \
    int rin = lane >> 2; \
    int ksl = (lane & 3) ^ ((lane >> 3) & 3);   /* swizzled source k-slot */ \
    int u0r = wid * 32; \
    const u16* Ag0 = (Asrc) + (size_t)(m0 + u0r + rin) * KDIM + ksl * 8; \
    const u16* Ag1 = (Asrc) + (size_t)(m0 + u0r + 16 + rin) * KDIM + ksl * 8; \
    const u16* Bg0 = (Bsrc) + (size_t)(n0 + u0r + rin) * KDIM + ksl * 8; \
    const u16* Bg1 = (Bsrc) + (size_t)(n0 + u0r + 16 + rin) * KDIM + ksl * 8; \
    int xquad = quad ^ ((l16 >> 1) & 3);        /* swizzled read slot */

#define GEMM_STAGE(Abuf, Bbuf, kk) \
    GLOAD16(Ag0 + (kk), &Abuf[u0r * 32]); \
    GLOAD16(Ag1 + (kk), &Abuf[(u0r + 16) * 32]); \
    GLOAD16(Bg0 + (kk), &Bbuf[u0r * 32]); \
    GLOAD16(Bg1 + (kk), &Bbuf[(u0r + 16) * 32]);

#define GEMM_COMPUTE(Abuf, Bbuf, F16) { \
    Frag af[4], bf[4]; \
    for (int i = 0; i < 4; i++) \
        af[i].s = *(const short8*)&Abuf[(wr * 64 + i * 16 + l16) * 32 + xquad * 8]; \
    for (int j = 0; j < 4; j++) \
        bf[j].s = *(const short8*)&Bbuf[(wc * 64 + j * 16 + l16) * 32 + xquad * 8]; \
    for (int i = 0; i < 4; i++) \
        for (int j = 0; j < 4; j++) { \
            if (F16) \
                acc[i][j] = __builtin_amdgcn_mfma_f32_16x16x32_f16(af[i].h, bf[j].h, acc[i][j], 0, 0, 0); \
            else \
                acc[i][j] = __builtin_amdgcn_mfma_f32_16x16x32_bf16(af[i].s, bf[j].s, acc[i][j], 0, 0, 0); \
        } \
}

#define GEMM_PHASE(Ac, Bc, An, Bn, tt, F16) \
    GEMM_STAGE(An, Bn, ((tt) + 2) * 32) \
    GEMM_WAITBAR8() \
    GEMM_COMPUTE(Ac, Bc, F16) \
    GEMM_READBAR()

#define GEMM_MAINLOOP(F16) \
    GEMM_STAGE(A0s, B0s, 0) \
    GEMM_STAGE(A1s, B1s, 32) \
    for (int t = 0; t < 60; t += 3) { \
        GEMM_PHASE(A0s, B0s, A2s, B2s, t,     F16) \
        GEMM_PHASE(A1s, B1s, A0s, B0s, t + 1, F16) \
        GEMM_PHASE(A2s, B2s, A1s, B1s, t + 2, F16) \
    } \
    GEMM_PHASE(A0s, B0s, A2s, B2s, 60, F16)   /* stages substep 62 */ \
    GEMM_PHASE(A1s, B1s, A0s, B0s, 61, F16)   /* stages substep 63 */ \
    GEMM_WAITBAR4() \
    GEMM_COMPUTE(A2s, B2s, F16)               /* substep 62 */ \
    GEMM_READBAR() \
    GEMM_WAITBAR0() \
    GEMM_COMPUTE(A0s, B0s, F16)               /* substep 63 */

// ---------------- fused Q+K+V projection: 1D grid of 768 equal-cost blocks ----------------
// XCD-aware swizzle (T1): 768%8==0, bijective chunk map lin=(bid&7)*96+(bid>>3)
// (FETCH 112->78MB measured in R9).
// lin <  512: Q:  C[t,d] = xh @ wqt^T, rope -> [B,NH,T,D]
// 512..639 : K:  C[t,d] = xh @ wkt^T, rope -> [B,NKV,T,D]
// 640..767 : V^T by operand swap: A = wvt (rows d=512), Bt = xh (rows t=4096)
//            -> C[d,t], write [B,NKV,D,T] coalesced along t.
__global__ __launch_bounds__(256)
void gemm_qkv(const u16* __restrict__ xh, const u16* __restrict__ wqt,
              const u16* __restrict__ wkt, const u16* __restrict__ wvt,
              const float* __restrict__ bq, const float* __restrict__ bk,
              const float* __restrict__ bv,
              u16* __restrict__ qout, u16* __restrict__ kout, u16* __restrict__ vout,
              const float* __restrict__ ctab, const float* __restrict__ stab) {
    __shared__ u16 A0s[128 * 32], A1s[128 * 32], A2s[128 * 32];
    __shared__ u16 B0s[128 * 32], B1s[128 * 32], B2s[128 * 32];
    int tid = threadIdx.x;
    int wid = tid >> 6, lane = tid & 63;
    int quad = lane >> 4, l16 = lane & 15;
    int wr = wid >> 1, wc = wid & 1;

    int bid = blockIdx.x;
    int lin = (bid & 7) * 96 + (bid >> 3);   // XCD swizzle, bijective on 768
    int mode, m0, n0;
    const u16 *A, *Bt;
    if (lin < 512) {          // Q
        mode = 0; m0 = (lin >> 4) * 128; n0 = (lin & 15) * 128; A = xh; Bt = wqt;
    } else if (lin < 640) {   // K
        int i = lin - 512;
        mode = 1; m0 = (i >> 2) * 128; n0 = (i & 3) * 128; A = xh; Bt = wkt;
    } else {                  // V (swapped)
        int i = lin - 640;
        mode = 2; m0 = (i & 3) * 128; n0 = (i >> 2) * 128; A = wvt; Bt = xh;
    }

    float4v acc[4][4];
    for (int i = 0; i < 4; i++) for (int j = 0; j < 4; j++) acc[i][j] = (float4v){0,0,0,0};

    GEMM_STAGE_DECL(A, Bt)
    GEMM_MAINLOOP(true)

    if (mode == 2) {
        // rows m = global d (h = m>>7, d = m&127); cols = global t (b = col>>11)
        for (int i = 0; i < 4; i++) {
            int mbase = m0 + wr * 64 + i * 16 + quad * 4;
            float brow[4];
            for (int r = 0; r < 4; r++) brow[r] = bv[mbase + r];
            for (int j = 0; j < 4; j++) {
                int col = n0 + wc * 64 + j * 16 + l16;
                int b = col >> 11, t = col & 2047;
                for (int r = 0; r < 4; r++) {
                    int m = mbase + r;
                    float val = acc[i][j][r] + brow[r];
                    vout[(((size_t)(b * NKV + (m >> 7))) * HD + (m & 127)) * T_SEQ + t] = f32_bf16(val);
                }
            }
        }
    } else {
        const float* bias = mode ? bk : bq;
        u16* outU = mode ? kout : qout;
        int nheads = mode ? NKV : NH;
        for (int i = 0; i < 4; i++) {
            int mbase = m0 + wr * 64 + i * 16 + quad * 4;
            for (int j = 0; j < 4; j++) {
                int col = n0 + wc * 64 + j * 16 + l16;
                float bcol = bias[col];
                for (int r = 0; r < 4; r++) {
                    int m = mbase + r;
                    float val = acc[i][j][r] + bcol;
                    int b = m >> 11, t = m & 2047;
                    int h = col >> 7, d = col & 127;
                    int jj = d >> 1;
                    float c = ctab[t * 64 + jj];
                    float s = stab[t * 64 + jj];
                    float partner = __shfl_xor(val, 1, 64);
                    float o = (d & 1) ? (partner * s + val * c) : (val * c - partner * s);
                    outU[(((size_t)(b * nheads + h)) * T_SEQ + t) * HD + d] = f32_bf16(o);
                }
            }
        }
    }
}

// ---------------- output projection GEMM (bf16 in, fp32 + bias out) ----------------
// 1-D grid of 512 with the same XCD swizzle (512%8==0, cpx=64).
__global__ __launch_bounds__(256)
void gemm_out(const u16* __restrict__ A, const u16* __restrict__ Bt,
              const float* __restrict__ bias, float* __restrict__ outF) {
    __shared__ u16 A0s[128 * 32], A1s[128 * 32], A2s[128 * 32];
    __shared__ u16 B0s[128 * 32], B1s[128 * 32], B2s[128 * 32];
    int tid = threadIdx.x;
    int wid = tid >> 6, lane = tid & 63;
    int quad = lane >> 4, l16 = lane & 15;
    int wr = wid >> 1, wc = wid & 1;
    int bid = blockIdx.x;
    int lin = (bid & 7) * 64 + (bid >> 3);   // XCD swizzle, bijective on 512
    int m0 = (lin >> 4) * 128, n0 = (lin & 15) * 128;

    float4v acc[4][4];
    for (int i = 0; i < 4; i++) for (int j = 0; j < 4; j++) acc[i][j] = (float4v){0,0,0,0};

    GEMM_STAGE_DECL(A, Bt)
    GEMM_MAINLOOP(false)

    for (int i = 0; i < 4; i++) {
        int mbase = m0 + wr * 64 + i * 16 + quad * 4;
        for (int j = 0; j < 4; j++) {
            int col = n0 + wc * 64 + j * 16 + l16;
            float bcol = bias[col];
            for (int r = 0; r < 4; r++)
                outF[(size_t)(mbase + r) * NE + col] = acc[i][j][r] + bcol;
        }
    }
}

// ---------------- flash attention v4 + fused Wo transpose tail ----------------
// attn path (bid < 512) byte-identical to R13. bid in [512, 4608): Wo
// transpose blocks (f32 -> bf16 into wot). wqt (=wot) is dead by this launch
// (the qkv launch boundary is the fence), and attn's 512 variable-duration
// blocks leave CU tail idle that these 4096 tiny blocks fill for free --
// removes the separate transpose_wo launch AND its launch gap. Disjoint
// buffers (attn: qr/kr/vt->ao; transpose: Wo->wot), so any block interleave
// is correct. smem reused as the f32 tile (aligned, 4224B <= 35840B).
__global__ __launch_bounds__(256, 2)
void attn_kernel(const u16* __restrict__ Qr, const u16* __restrict__ Kr,
                 const u16* __restrict__ Vt, u16* __restrict__ Oout,
                 const float* __restrict__ Wo, u16* __restrict__ wot) {
    __shared__ __align__(16) u16 smem[17920];   // 35840 B
    u16* klds = smem;                      // K tile [s=64][d=128] stride 136
    u16* vlds = smem + 8704;               // V^T tile [d=128][s=64] stride 72
    int tid = threadIdx.x;

    int bid = blockIdx.x;
    if (bid >= 512) {                      // ---- Wo transpose tail block ----
        int tb = bid - 512;                // [0, 4096)
        int n0 = (tb & 63) * 32, k0 = (tb >> 6) * 32;
        int tx = tid & 31, ty = tid >> 5;  // 32 x 8
        float* tile = (float*)smem;        // [32][33]
        for (int i = 0; i < 32; i += 8)
            tile[(ty + i) * 33 + tx] = Wo[(size_t)(k0 + ty + i) * 2048 + n0 + tx];
        __syncthreads();
        for (int i = 0; i < 32; i += 8)
            wot[(size_t)(n0 + ty + i) * 2048 + k0 + tx] = f32_bf16(tile[tx * 33 + ty + i]);
        return;
    }

    int wid = tid >> 6, lane = tid & 63;
    int l32 = lane & 31, hh = lane >> 5;

    int lin = bid;
    int g = lin >> 5, bh = lin & 31;
    int qt = (lin < 256) ? (15 - g) : (g - 8);   // balance: CU gets qt and 15-qt
    int b = bh >> 4, hd = bh & 15, kvh = hd >> 2;
    int t0 = qt * 128;

    const u16* Qb = Qr + (((size_t)(b * NH + hd)) * T_SEQ + t0 + wid * 32) * HD;
    const u16* Kb = Kr + ((size_t)(b * NKV + kvh)) * T_SEQ * HD;
    const u16* Vb = Vt + ((size_t)(b * NKV + kvh)) * HD * T_SEQ;

    // Q as B-operand frags: col = t = l32, k = d
    short8 qf[8];
#pragma unroll
    for (int ks = 0; ks < 8; ks++)
        qf[ks] = *(const short8*)(Qb + (size_t)l32 * HD + ks * 16 + hh * 8);

    float16v oacc[4];   // O^T: rows d (dt*32 block), cols t (= l32)
#pragma unroll
    for (int dt = 0; dt < 4; dt++)
        oacc[dt] = (float16v){0,0,0,0,0,0,0,0,0,0,0,0,0,0,0,0};
    float m_run = -INFINITY, l_run = 0.f;

    int ksr = tid >> 2, kc = (tid & 3) * 32;   // K staging: row s, col base (u16)
    int vdr = tid >> 1, vc = (tid & 1) * 32;   // V staging: row d, col base (u16)

    int nst = 2 * qt + 2;

    {   // prologue: stage tile 0
        const u16* ksrc = Kb + (size_t)ksr * HD + kc;
        const u16* vsrc = Vb + (size_t)vdr * T_SEQ + vc;
        short8 kr0[4], vr0[4];
#pragma unroll
        for (int i = 0; i < 4; i++) kr0[i] = *(const short8*)(ksrc + i * 8);
#pragma unroll
        for (int i = 0; i < 4; i++) vr0[i] = *(const short8*)(vsrc + i * 8);
#pragma unroll
        for (int i = 0; i < 4; i++) *(short8*)&klds[ksr * 136 + kc + i * 8] = kr0[i];
#pragma unroll
        for (int i = 0; i < 4; i++) *(short8*)&vlds[vdr * 72 + vc + i * 8] = vr0[i];
    }
    __syncthreads();

    for (int st = 0; st < nst; st++) {
        short8 krg[4], vrg[4];
        bool more = (st + 1 < nst);
        if (more) {   // prefetch next K/V tile into registers
            const u16* ksrc = Kb + ((size_t)(st + 1) * 64 + ksr) * HD + kc;
            const u16* vsrc = Vb + (size_t)vdr * T_SEQ + (st + 1) * 64 + vc;
#pragma unroll
            for (int i = 0; i < 4; i++) krg[i] = *(const short8*)(ksrc + i * 8);
#pragma unroll
            for (int i = 0; i < 4; i++) vrg[i] = *(const short8*)(vsrc + i * 8);
        }

        // wave-uniform skip: tile entirely above this wave's causal diagonal
        // (only st == 2qt+1 for waves 0,1). Barriers stay outside.
        bool active = (st * 64) <= (t0 + wid * 32 + 31);
        if (active) {
            // S^T = K * Q^T : rows = s (2 tiles of 32), cols = t (32)
            float16v sfa[2];
            sfa[0] = (float16v){0,0,0,0,0,0,0,0,0,0,0,0,0,0,0,0};
            sfa[1] = (float16v){0,0,0,0,0,0,0,0,0,0,0,0,0,0,0,0};
            __builtin_amdgcn_s_setprio(1);
#pragma unroll
            for (int ks = 0; ks < 8; ks++) {
                short8 kf0 = *(const short8*)&klds[l32 * 136 + ks * 16 + hh * 8];
                short8 kf1 = *(const short8*)&klds[(32 + l32) * 136 + ks * 16 + hh * 8];
                sfa[0] = __builtin_amdgcn_mfma_f32_32x32x16_bf16(kf0, qf[ks], sfa[0], 0, 0, 0);
                sfa[1] = __builtin_amdgcn_mfma_f32_32x32x16_bf16(kf1, qf[ks], sfa[1], 0, 0, 0);
            }
            __builtin_amdgcn_s_setprio(0);

            int tg = t0 + wid * 32 + l32;
            if (st >= 2 * qt) {   // causal mask on diagonal tiles
#pragma unroll
                for (int stile = 0; stile < 2; stile++)
#pragma unroll
                    for (int r = 0; r < 16; r++) {
                        int s = st * 64 + stile * 32 + (r & 3) + 8 * (r >> 2) + 4 * hh;
                        if (s > tg) sfa[stile][r] = -INFINITY;
                    }
            }

            // online softmax over s; T13 defer-max: skip O-rescale while the
            // tile max stays within 8 of the running max (P bounded by e^8).
            float mx = -INFINITY;
#pragma unroll
            for (int stile = 0; stile < 2; stile++)
#pragma unroll
                for (int r = 0; r < 16; r++) mx = fmaxf(mx, sfa[stile][r]);
            mx = fmaxf(mx, __shfl_xor(mx, 32, 64));
            bool nos = __all(mx - m_run <= 8.f);   // wave-uniform
            float mnew = nos ? m_run : fmaxf(m_run, mx);
            float alpha = nos ? 1.f : __expf(m_run - mnew);
            float psum = 0.f;
#pragma unroll
            for (int stile = 0; stile < 2; stile++)
#pragma unroll
                for (int r = 0; r < 16; r++) {
                    float p = __expf(sfa[stile][r] - mnew);
                    sfa[stile][r] = p;
                    psum += p;
                }
            psum += __shfl_xor(psum, 32, 64);
            l_run = l_run * alpha + psum;
            m_run = mnew;

            if (!nos) {
#pragma unroll
                for (int dt = 0; dt < 4; dt++)
#pragma unroll
                    for (int r = 0; r < 16; r++) oacc[dt][r] *= alpha;
            }

            // T12: P^T -> B-operand fragments entirely in registers.
            // Accumulator holds s_local=(r&3)+8(r>>2)+4hh; the B-operand needs
            // k=s=hh*8+e per 16-block. swap(P0,P2)/(P1,P3) redistributes the
            // 4-element groups across the lane halves: after swap,
            // P0=[lo|lo'], P2=[hi|hi'] which is exactly word0/word2 for both hh.
            __builtin_amdgcn_s_setprio(1);
#pragma unroll
            for (int g2 = 0; g2 < 4; g2++) {           // s16-block = ks2
                int stile = g2 >> 1, gg = g2 & 1;
                uint32_t P0 = cvtpk_bf16(sfa[stile][8 * gg + 0], sfa[stile][8 * gg + 1]);
                uint32_t P1 = cvtpk_bf16(sfa[stile][8 * gg + 2], sfa[stile][8 * gg + 3]);
                uint32_t P2 = cvtpk_bf16(sfa[stile][8 * gg + 4], sfa[stile][8 * gg + 5]);
                uint32_t P3 = cvtpk_bf16(sfa[stile][8 * gg + 6], sfa[stile][8 * gg + 7]);
                perm32swap(P0, P2);
                perm32swap(P1, P3);
                union { uint32_t w[4]; short8 s; } pf;
                pf.w[0] = P0; pf.w[1] = P1; pf.w[2] = P2; pf.w[3] = P3;
#pragma unroll
                for (int dt = 0; dt < 4; dt++) {
                    short8 vf = *(const short8*)&vlds[(dt * 32 + l32) * 72 + g2 * 16 + hh * 8];
                    oacc[dt] = __builtin_amdgcn_mfma_f32_32x32x16_bf16(vf, pf.s, oacc[dt], 0, 0, 0);
                }
            }
            __builtin_amdgcn_s_setprio(0);
        }

        __syncthreads();   // all K/V reads done before overwrite
        if (more) {
#pragma unroll
            for (int i = 0; i < 4; i++) *(short8*)&klds[ksr * 136 + kc + i * 8] = krg[i];
#pragma unroll
            for (int i = 0; i < 4; i++) *(short8*)&vlds[vdr * 72 + vc + i * 8] = vrg[i];
        }
        __syncthreads();   // staging visible before next iteration's reads
    }

    // epilogue: scale (per-lane), transpose O^T -> O via LDS scratch
    const float scale = 0.022097086912079608f;   // 2048^-0.5
    float sc = scale / l_run;
    u16* ow = smem + wid * 4352;           // [t=32][d=128] stride 136
#pragma unroll
    for (int dt = 0; dt < 4; dt++)
#pragma unroll
        for (int gq = 0; gq < 4; gq++) {
            ushort4v pk;
            pk.x = f32_bf16(oacc[dt][gq * 4 + 0] * sc);
            pk.y = f32_bf16(oacc[dt][gq * 4 + 1] * sc);
            pk.z = f32_bf16(oacc[dt][gq * 4 + 2] * sc);
            pk.w = f32_bf16(oacc[dt][gq * 4 + 3] * sc);
            *(ushort4v*)&ow[l32 * 136 + dt * 32 + gq * 8 + hh * 4] = pk;
        }
    __syncthreads();   // transpose writes visible before read-back
    int tl = lane >> 4, dcol = (lane & 15) * 8;
#pragma unroll
    for (int ch = 0; ch < 8; ch++) {
        int t_local = tl + ch * 4;
        short8 ov = *(const short8*)&ow[t_local * 136 + dcol];
        *(short8*)&Oout[((size_t)(b * T_SEQ) + t0 + wid * 32 + t_local) * NE + hd * HD + dcol] = ov;
    }
}

// ---------------- launch ----------------
extern "C" void kernel_launch(void* const* d_in, const int* in_sizes, int n_in,
                              void* d_out, int out_size, void* d_ws, size_t ws_size,
                              hipStream_t stream) {
    const float* x  = (const float*)d_in[0];
    const float* Wq = (const float*)d_in[1];
    const float* bq = (const float*)d_in[2];
    const float* Wk = (const float*)d_in[3];
    const float* bk = (const float*)d_in[4];
    const float* Wv = (const float*)d_in[5];
    const float* bv = (const float*)d_in[6];
    const float* Wo = (const float*)d_in[7];
    const float* bo = (const float*)d_in[8];
    float* out = (float*)d_out;
    char* ws = (char*)d_ws;

    // aliasing: ao reuses xh (xh dead after QKV gemm); wot reuses wqt (dead after QKV gemm)
    u16* xh   = (u16*)(ws);                      // 16 MB   [also ao]
    u16* wqt  = (u16*)(ws + 16777216);           // 8 MB    [also wot]
    u16* wkt  = (u16*)(ws + 25165824);           // 2 MB
    u16* wvt  = (u16*)(ws + 27262976);           // 2 MB
    u16* qr   = (u16*)(ws + 29360128);           // 16 MB
    u16* kr   = (u16*)(ws + 46137344);           // 4 MB
    u16* vt   = (u16*)(ws + 50331648);           // 4 MB
    float* ctab = (float*)(ws + 54525952);       // 0.5 MB
    float* stab = (float*)(ws + 55050240);       // 0.5 MB
    u16* ao  = xh;
    u16* wot = wqt;

    conv_f16<<<dim3(8192), 256, 0, stream>>>(x, xh);
    prep_wt<<<dim3(6656), 256, 0, stream>>>(Wq, wqt, Wk, wkt, Wv, wvt, ctab, stab);

    gemm_qkv<<<dim3(768), 256, 0, stream>>>(xh, wqt, wkt, wvt, bq, bk, bv,
                                            qr, kr, vt, ctab, stab);

    // attn + Wo-transpose tail blocks in one launch (wqt dead after gemm_qkv;
    // the 4096 tiny transpose blocks fill attn's variable-duration tail)
    attn_kernel<<<dim3(4608), 256, 0, stream>>>(qr, kr, vt, ao, Wo, wot);

    gemm_out<<<dim3(512), 256, 0, stream>>>(ao, wot, bo, out);
}